// Round 1
// baseline (34.618 us; speedup 1.0000x reference)
//
#include <hip/hip_runtime.h>
#include <hip/hip_bf16.h>

// ConvNeXtLoss: fused attention-BCE + dice + reverse-dice over (16,4,512,512).
// Pass 1: per-(b,c)-plane partial sums (6 quantities), 2048 blocks write
//         block-partials to workspace (no atomics -> deterministic).
// Pass 2: 64-lane finalize combines plane sums, computes per-batch alpha,
//         dice / rev-dice terms, writes scalar loss.

#define B_DIM 16
#define C_DIM 4
#define HW 262144            // 512*512 plane
#define NPLANES 64           // B*C
#define K_CHUNKS 32          // blocks per plane
#define CHUNK (HW / K_CHUNKS)  // 8192 elements per block
#define NBLOCKS (NPLANES * K_CHUNKS)  // 2048
#define NSUMS 6

__global__ __launch_bounds__(256) void loss_main(
    const float* __restrict__ pred, const int* __restrict__ label,
    float* __restrict__ ws) {
  const int block = blockIdx.x;          // 0..2047
  const int plane = block >> 5;          // /K_CHUNKS
  const int chunk = block & (K_CHUNKS - 1);
  const long base = (long)plane * HW + (long)chunk * CHUNK;
  const float4* p4 = (const float4*)(pred + base);
  const int4*   t4 = (const int4*)(label + base);
  const int tid = threadIdx.x;

  float s_pt = 0.f, s_pp = 0.f, s_t = 0.f, s_p = 0.f, sum1 = 0.f, sum2 = 0.f;

#pragma unroll
  for (int it = 0; it < CHUNK / 4 / 256; ++it) {  // 8 iterations
    float4 p = p4[tid + it * 256];
    int4 t = t4[tid + it * 256];
    float pe[4] = {p.x, p.y, p.z, p.w};
    int te[4] = {t.x, t.y, t.z, t.w};
#pragma unroll
    for (int j = 0; j < 4; ++j) {
      float pv = pe[j];
      bool tv = (te[j] != 0);
      // p_clip = clip(p, 1e-14, 1-1e-14); 1-1e-14 rounds to 1.0f in f32
      float pc = fminf(fmaxf(pv, 1e-14f), 1.0f);
      // weight factor: 8^((1-pc)^0.5) if t else 8^(pc^0.5)  == exp2(3*sqrt(x))
      float x = tv ? (1.0f - pc) : pc;
      float Bw = exp2f(3.0f * sqrtf(x));
      // bce log term on RAW pred, clamped at -100 (log(0)=-inf -> -100)
      float arg = tv ? pv : (1.0f - pv);
      float L = fmaxf(__logf(arg), -100.0f);
      float contrib = -Bw * L;
      sum1 += tv ? contrib : 0.0f;   // alpha-weighted part
      sum2 += tv ? 0.0f : contrib;   // (1-alpha)-weighted part
      s_pt += tv ? pv : 0.0f;
      s_pp += pv * pv;
      s_t  += tv ? 1.0f : 0.0f;
      s_p  += pv;
    }
  }

  // wave reduce (64 lanes), then cross-wave via LDS
  float vals[NSUMS] = {s_pt, s_pp, s_t, s_p, sum1, sum2};
  __shared__ float lds[4][NSUMS];
#pragma unroll
  for (int q = 0; q < NSUMS; ++q) {
    float v = vals[q];
#pragma unroll
    for (int off = 32; off; off >>= 1) v += __shfl_down(v, off);
    vals[q] = v;
  }
  const int wave = tid >> 6;
  if ((tid & 63) == 0) {
#pragma unroll
    for (int q = 0; q < NSUMS; ++q) lds[wave][q] = vals[q];
  }
  __syncthreads();
  if (tid < NSUMS) {
    float v = lds[0][tid] + lds[1][tid] + lds[2][tid] + lds[3][tid];
    ws[block * NSUMS + tid] = v;
  }
}

__global__ __launch_bounds__(64) void loss_finalize(
    const float* __restrict__ ws, float* __restrict__ out) {
  const int p = threadIdx.x;  // plane index 0..63 ; b = p>>2, c = p&3
  float s[NSUMS] = {0.f, 0.f, 0.f, 0.f, 0.f, 0.f};
  for (int k = 0; k < K_CHUNKS; ++k) {
    const float* w = ws + (p * K_CHUNKS + k) * NSUMS;
#pragma unroll
    for (int q = 0; q < NSUMS; ++q) s[q] += w[q];
  }
  const float s_pt = s[0], s_pp = s[1], s_t = s[2], s_p = s[3];
  const float sum1 = s[4], sum2 = s[5];
  const float N = (float)HW;
  const float SM = 1e-6f;

  // dice (per plane): 1 - (2*inter + S)/(sum p^2 + sum t + S)   [t^2 = t]
  float dice = 1.0f - (2.0f * s_pt + SM) / (s_pp + s_t + SM);
  // reverse dice via algebraic identities
  float inter2 = N - s_p - s_t + s_pt;
  float denom2 = 2.0f * N - 2.0f * s_p + s_pp - s_t;
  float rdice = 1.0f - (2.0f * inter2 + SM) / (denom2 + SM);

  // per-batch num_pos: sum s_t over the 4 channel lanes (p groups of 4)
  float np4 = s_t + __shfl_xor(s_t, 1);
  np4 += __shfl_xor(np4, 2);
  const float total = (float)(C_DIM * HW);  // 1048576
  float alpha = (total - np4) / total;

  float val = alpha * sum1 + (1.0f - alpha) * sum2
            + 2500.0f * (dice + rdice);   // DICE_COEFF == REV_DICE_COEFF

#pragma unroll
  for (int off = 32; off; off >>= 1) val += __shfl_down(val, off);
  if (p == 0) out[0] = val;
}

extern "C" void kernel_launch(void* const* d_in, const int* in_sizes, int n_in,
                              void* d_out, int out_size, void* d_ws, size_t ws_size,
                              hipStream_t stream) {
  const float* pred = (const float*)d_in[0];
  const int* label = (const int*)d_in[1];
  float* out = (float*)d_out;
  float* ws = (float*)d_ws;  // needs NBLOCKS*NSUMS*4 = 48 KiB

  loss_main<<<NBLOCKS, 256, 0, stream>>>(pred, label, ws);
  loss_finalize<<<1, 64, 0, stream>>>(ws, out);
}

// Round 2
// 28.161 us; speedup vs baseline: 1.2293x; 1.2293x over previous
//
#include <hip/hip_runtime.h>
#include <hip/hip_bf16.h>

// ConvNeXtLoss: fused attention-BCE + dice + reverse-dice over (16,4,512,512).
// Pass 1: per-(b,c)-plane partial sums (6 quantities), 2048 blocks write
//         block-partials to workspace (no atomics -> deterministic).
// Pass 2: 64-lane finalize combines plane sums, computes per-batch alpha,
//         dice / rev-dice terms, writes scalar loss.
//
// R2 changes vs R1 (which was 34.6 us, VALU-issue ~22 us >> 6 us hand count):
//  - raw __builtin_amdgcn_{sqrtf,exp2f,logf} instead of libm (no IEEE fixup
//    expansion; v_log_f32 is log2 so scale by ln2)
//  - branch-free inner math: tf=(float)t; arg=fma(p,1-2tf,tf); x=1-arg.
//    The reference clip(p,1e-14,1-1e-14) is absorbed: differs only at
//    p<1e-14 by <=2e-7 relative in the 8^sqrt term. sum2 derived as
//    sum_tot - sum1 in finalize.
//  - 2-deep explicit load prefetch, VGPR kept <=64 for 8 waves/SIMD.

#define B_DIM 16
#define C_DIM 4
#define HW 262144            // 512*512 plane
#define NPLANES 64           // B*C
#define K_CHUNKS 32          // blocks per plane
#define CHUNK (HW / K_CHUNKS)  // 8192 elements per block
#define NBLOCKS (NPLANES * K_CHUNKS)  // 2048
#define NSUMS 6
#define NITER (CHUNK / 4 / 256)  // 8

__global__ __launch_bounds__(256) void loss_main(
    const float* __restrict__ pred, const int* __restrict__ label,
    float* __restrict__ ws) {
  const int block = blockIdx.x;          // 0..2047
  const int plane = block >> 5;          // /K_CHUNKS
  const int chunk = block & (K_CHUNKS - 1);
  const long base = (long)plane * HW + (long)chunk * CHUNK;
  const float4* p4 = (const float4*)(pred + base);
  const int4*   t4 = (const int4*)(label + base);
  const int tid = threadIdx.x;

  float s_pt = 0.f, s_pp = 0.f, s_p = 0.f;
  float nsum_t = 0.f;   // sum over ALL elems of  Bw * (-L)  (positive)
  float nsum_1 = 0.f;   // sum over t==1 elems of Bw * (-L)
  int   s_ti = 0;       // integer count of positives

  float4 p_cur = p4[tid];
  int4   t_cur = t4[tid];

#pragma unroll
  for (int it = 0; it < NITER; ++it) {
    float4 p_nxt; int4 t_nxt;
    if (it + 1 < NITER) {
      p_nxt = p4[tid + (it + 1) * 256];
      t_nxt = t4[tid + (it + 1) * 256];
    }
    float pe[4] = {p_cur.x, p_cur.y, p_cur.z, p_cur.w};
    int   te[4] = {t_cur.x, t_cur.y, t_cur.z, t_cur.w};
#pragma unroll
    for (int j = 0; j < 4; ++j) {
      float pv = pe[j];
      float tf = (float)te[j];                    // labels are exactly 0/1
      // arg = t ? p : 1-p   (branch-free)
      float u   = __builtin_fmaf(tf, -2.0f, 1.0f);   // 1-2t
      float arg = __builtin_fmaf(pv, u, tf);         // p*(1-2t)+t
      float x   = 1.0f - arg;                        // t ? 1-p : p
      // Bw = 8^sqrt(x) = 2^(3*sqrt(x))
      float r  = __builtin_amdgcn_sqrtf(x);
      float Bw = __builtin_amdgcn_exp2f(3.0f * r);
      // L = max(ln(arg), -100); v_log_f32 is log2 -> scale by ln2
      float lg = __builtin_amdgcn_logf(arg);
      float L  = fmaxf(0.69314718056f * lg, -100.0f);
      float c  = Bw * (-L);                          // positive contribution
      nsum_t += c;
      nsum_1 = __builtin_fmaf(tf, c, nsum_1);
      s_pt   = __builtin_fmaf(tf, pv, s_pt);
      s_pp   = __builtin_fmaf(pv, pv, s_pp);
      s_p   += pv;
      s_ti  += te[j];
    }
    p_cur = p_nxt; t_cur = t_nxt;
  }

  float s_t = (float)s_ti;

  // wave reduce (64 lanes), then cross-wave via LDS
  float vals[NSUMS] = {s_pt, s_pp, s_t, s_p, nsum_1, nsum_t};
  __shared__ float lds[4][NSUMS];
#pragma unroll
  for (int q = 0; q < NSUMS; ++q) {
    float v = vals[q];
#pragma unroll
    for (int off = 32; off; off >>= 1) v += __shfl_down(v, off);
    vals[q] = v;
  }
  const int wave = tid >> 6;
  if ((tid & 63) == 0) {
#pragma unroll
    for (int q = 0; q < NSUMS; ++q) lds[wave][q] = vals[q];
  }
  __syncthreads();
  if (tid < NSUMS) {
    float v = lds[0][tid] + lds[1][tid] + lds[2][tid] + lds[3][tid];
    ws[block * NSUMS + tid] = v;
  }
}

__global__ __launch_bounds__(64) void loss_finalize(
    const float* __restrict__ ws, float* __restrict__ out) {
  const int p = threadIdx.x;  // plane index 0..63 ; b = p>>2, c = p&3
  float s[NSUMS] = {0.f, 0.f, 0.f, 0.f, 0.f, 0.f};
  for (int k = 0; k < K_CHUNKS; ++k) {
    const float* w = ws + (p * K_CHUNKS + k) * NSUMS;
#pragma unroll
    for (int q = 0; q < NSUMS; ++q) s[q] += w[q];
  }
  const float s_pt = s[0], s_pp = s[1], s_t = s[2], s_p = s[3];
  const float sum1 = s[4];             // sum over t==1 of Bw*(-L)
  const float sum2 = s[5] - s[4];      // sum over t==0 of Bw*(-L)
  const float N = (float)HW;
  const float SM = 1e-6f;

  // dice (per plane): 1 - (2*inter + S)/(sum p^2 + sum t + S)   [t^2 = t]
  float dice = 1.0f - (2.0f * s_pt + SM) / (s_pp + s_t + SM);
  // reverse dice via algebraic identities
  float inter2 = N - s_p - s_t + s_pt;
  float denom2 = 2.0f * N - 2.0f * s_p + s_pp - s_t;
  float rdice = 1.0f - (2.0f * inter2 + SM) / (denom2 + SM);

  // per-batch num_pos: sum s_t over the 4 channel lanes (p groups of 4)
  float np4 = s_t + __shfl_xor(s_t, 1);
  np4 += __shfl_xor(np4, 2);
  const float total = (float)(C_DIM * HW);  // 1048576
  float alpha = (total - np4) / total;

  float val = alpha * sum1 + (1.0f - alpha) * sum2
            + 2500.0f * (dice + rdice);   // DICE_COEFF == REV_DICE_COEFF

#pragma unroll
  for (int off = 32; off; off >>= 1) val += __shfl_down(val, off);
  if (p == 0) out[0] = val;
}

extern "C" void kernel_launch(void* const* d_in, const int* in_sizes, int n_in,
                              void* d_out, int out_size, void* d_ws, size_t ws_size,
                              hipStream_t stream) {
  const float* pred = (const float*)d_in[0];
  const int* label = (const int*)d_in[1];
  float* out = (float*)d_out;
  float* ws = (float*)d_ws;  // needs NBLOCKS*NSUMS*4 = 48 KiB

  loss_main<<<NBLOCKS, 256, 0, stream>>>(pred, label, ws);
  loss_finalize<<<1, 64, 0, stream>>>(ws, out);
}